// Round 6
// baseline (139.230 us; speedup 1.0000x reference)
//
#include <hip/hip_runtime.h>

// ShuffleNet unit, NCHW. B=64, Cin=Cout=480, mid=120, H=W=28, G=3.
// K1/K3: 1x1 grouped convs as MFMA GEMMs (bf16 split-precision, 3 passes ->
// ~fp32 accuracy). K2: depthwise 3x3 fp32 vector (cheap), shuffle folded in.

namespace {
constexpr int CIN = 480;
constexpr int MID = 120;
constexpr int HWP = 784;
constexpr float EPSV = 1e-5f;

constexpr int XRS = 168;   // K1 LDS row stride (bf16 units): 160 + 8 pad
constexpr int WRS = 168;
constexpr int K3RS = 72;   // K3 LDS row stride: 64 + 8 pad

constexpr int K1_SMEM = (64 * XRS * 2 + 48 * WRS * 2) * 2;   // 75264 B
constexpr int K3_SMEM = (32 * K3RS * 2 + 160 * K3RS * 2) * 2; // 55296 B
}

typedef short bf16x8 __attribute__((ext_vector_type(8)));
typedef float f32x4  __attribute__((ext_vector_type(4)));

__device__ inline unsigned short f2bf(float v) {
    unsigned u = __float_as_uint(v);
    return (unsigned short)((u + 0x7fffu + ((u >> 16) & 1u)) >> 16);
}
__device__ inline float bf2f(unsigned short s) {
    return __uint_as_float(((unsigned)s) << 16);
}
__device__ inline void split2(float v, unsigned short& h, unsigned short& l) {
    h = f2bf(v);
    l = f2bf(v - bf2f(h));
}

// ---------- K1: 1x1 grouped conv (480->120, G=3) + BN + ReLU, MFMA ----------
// grid (784, 3), block 256. px-tile 64 (N = 4 x 16), M = 40 (pad 48), K = 160.
__global__ __launch_bounds__(256) void k1_mfma(
    const float* __restrict__ x,  const float* __restrict__ w1,
    const float* __restrict__ g1, const float* __restrict__ b1,
    const float* __restrict__ m1, const float* __restrict__ v1,
    float* __restrict__ tmp1)
{
    extern __shared__ unsigned short sm[];
    unsigned short* xh = sm;
    unsigned short* xl = xh + 64 * XRS;
    unsigned short* wh = xl + 64 * XRS;
    unsigned short* wl = wh + 48 * WRS;

    const int tid  = threadIdx.x;
    const int lane = tid & 63;
    const int wv   = tid >> 6;          // 0..3
    const int g    = blockIdx.y;
    const int p0   = blockIdx.x * 64;
    const int b0   = p0 / HWP;
    const int r0   = p0 - b0 * HWP;

    // ---- stage x tile (64 px x 160 ic) as split bf16, K-major ----
    {
        int hw = r0 + lane, bb = b0;
        if (hw >= HWP) { hw -= HWP; ++bb; }
        const float* __restrict__ xb = x + (size_t)(bb * CIN + g * 160) * HWP + hw;
#pragma unroll
        for (int ii = 0; ii < 10; ++ii) {
            const int ic = wv * 40 + ii * 4;
            float v0 = xb[(size_t)(ic + 0) * HWP];
            float v1v = xb[(size_t)(ic + 1) * HWP];
            float v2 = xb[(size_t)(ic + 2) * HWP];
            float v3 = xb[(size_t)(ic + 3) * HWP];
            unsigned short h0, l0, h1, l1, h2, l2, h3, l3;
            split2(v0, h0, l0); split2(v1v, h1, l1);
            split2(v2, h2, l2); split2(v3, h3, l3);
            uint2 ph, pl;
            ph.x = (unsigned)h0 | ((unsigned)h1 << 16);
            ph.y = (unsigned)h2 | ((unsigned)h3 << 16);
            pl.x = (unsigned)l0 | ((unsigned)l1 << 16);
            pl.y = (unsigned)l2 | ((unsigned)l3 << 16);
            *reinterpret_cast<uint2*>(&xh[lane * XRS + ic]) = ph;
            *reinterpret_cast<uint2*>(&xl[lane * XRS + ic]) = pl;
        }
    }
    // ---- stage W tile (48 oc x 160 ic, rows 40..47 zero), K-major ----
    {
        const float* __restrict__ wb = w1 + (size_t)(g * 40) * 160;
#pragma unroll
        for (int it = 0; it < 8; ++it) {
            const int task = tid + it * 256;
            if (task < 1920) {
                const int oc  = task / 40;
                const int ic0 = (task - oc * 40) * 4;
                float4 wv4 = make_float4(0.f, 0.f, 0.f, 0.f);
                if (oc < 40)
                    wv4 = *reinterpret_cast<const float4*>(wb + oc * 160 + ic0);
                unsigned short h0, l0, h1, l1, h2, l2, h3, l3;
                split2(wv4.x, h0, l0); split2(wv4.y, h1, l1);
                split2(wv4.z, h2, l2); split2(wv4.w, h3, l3);
                uint2 ph, pl;
                ph.x = (unsigned)h0 | ((unsigned)h1 << 16);
                ph.y = (unsigned)h2 | ((unsigned)h3 << 16);
                pl.x = (unsigned)l0 | ((unsigned)l1 << 16);
                pl.y = (unsigned)l2 | ((unsigned)l3 << 16);
                *reinterpret_cast<uint2*>(&wh[oc * WRS + ic0]) = ph;
                *reinterpret_cast<uint2*>(&wl[oc * WRS + ic0]) = pl;
            }
        }
    }
    __syncthreads();

    // ---- MFMA: D[48 x 16] per wave (wave = N-tile), 5 K-steps, 3 passes ----
    f32x4 acc[3];
#pragma unroll
    for (int mt = 0; mt < 3; ++mt) acc[mt] = f32x4{0.f, 0.f, 0.f, 0.f};

    const int n16  = lane & 15;
    const int koff = (lane >> 4) * 8;
    const int brow = wv * 16 + n16;
#pragma unroll
    for (int ks = 0; ks < 5; ++ks) {
        const int k0 = ks * 32 + koff;
        const bf16x8 Bh = *reinterpret_cast<bf16x8*>(&xh[brow * XRS + k0]);
        const bf16x8 Bl = *reinterpret_cast<bf16x8*>(&xl[brow * XRS + k0]);
#pragma unroll
        for (int mt = 0; mt < 3; ++mt) {
            const bf16x8 Ah = *reinterpret_cast<bf16x8*>(&wh[(mt * 16 + n16) * WRS + k0]);
            const bf16x8 Al = *reinterpret_cast<bf16x8*>(&wl[(mt * 16 + n16) * WRS + k0]);
            acc[mt] = __builtin_amdgcn_mfma_f32_16x16x32_bf16(Ah, Bh, acc[mt], 0, 0, 0);
            acc[mt] = __builtin_amdgcn_mfma_f32_16x16x32_bf16(Ah, Bl, acc[mt], 0, 0, 0);
            acc[mt] = __builtin_amdgcn_mfma_f32_16x16x32_bf16(Al, Bh, acc[mt], 0, 0, 0);
        }
    }

    // ---- epilogue: BN + ReLU, store fp32 tmp1 ----
    {
        const int pj = wv * 16 + n16;
        int hw = r0 + pj, bb = b0;
        if (hw >= HWP) { hw -= HWP; ++bb; }
        const int rb = (lane >> 4) * 4;
#pragma unroll
        for (int mt = 0; mt < 3; ++mt) {
#pragma unroll
            for (int r = 0; r < 4; ++r) {
                const int ocl = mt * 16 + rb + r;
                if (ocl < 40) {
                    const int oc = g * 40 + ocl;
                    const float s  = g1[oc] * rsqrtf(v1[oc] + EPSV);
                    const float sh = fmaf(-m1[oc], s, b1[oc]);
                    float val = fmaf(acc[mt][r], s, sh);
                    tmp1[(size_t)(bb * MID + oc) * HWP + hw] = val > 0.f ? val : 0.f;
                }
            }
        }
    }
}

// ---------- K2: depthwise 3x3 + BN, shuffle folded into write (fp32) ----------
__global__ __launch_bounds__(256) void k2_dw(
    const float* __restrict__ tmp1, const float* __restrict__ w2,
    const float* __restrict__ g2,   const float* __restrict__ b2,
    const float* __restrict__ m2,   const float* __restrict__ v2,
    float* __restrict__ tmp2)
{
    const int t  = blockIdx.x * 256 + threadIdx.x;
    const int b  = t / 196;
    const int hw = (t - b * 196) * 4;
    const int h  = hw / 28;
    const int w  = hw - h * 28;
    const int c  = blockIdx.y;
    const float* __restrict__ in = tmp1 + (size_t)(b * MID + c) * HWP;

    float wk[9];
#pragma unroll
    for (int i = 0; i < 9; ++i) wk[i] = w2[c * 9 + i];

    float a0 = 0.f, a1 = 0.f, a2 = 0.f, a3 = 0.f;
#pragma unroll
    for (int dh = -1; dh <= 1; ++dh) {
        const int hh = h + dh;
        if (hh < 0 || hh > 27) continue;
        const float* r = in + hh * 28 + w;
        const float4 c4 = *reinterpret_cast<const float4*>(r);
        const float cl = (w > 0)  ? r[-1] : 0.f;
        const float cr = (w < 24) ? r[4]  : 0.f;
        const float* wr = wk + (dh + 1) * 3;
        a0 = fmaf(cl,   wr[0], a0); a0 = fmaf(c4.x, wr[1], a0); a0 = fmaf(c4.y, wr[2], a0);
        a1 = fmaf(c4.x, wr[0], a1); a1 = fmaf(c4.y, wr[1], a1); a1 = fmaf(c4.z, wr[2], a1);
        a2 = fmaf(c4.y, wr[0], a2); a2 = fmaf(c4.z, wr[1], a2); a2 = fmaf(c4.w, wr[2], a2);
        a3 = fmaf(c4.z, wr[0], a3); a3 = fmaf(c4.w, wr[1], a3); a3 = fmaf(cr,   wr[2], a3);
    }
    const float s  = g2[c] * rsqrtf(v2[c] + EPSV);
    const float sh = fmaf(-m2[c], s, b2[c]);
    const int gi = c / 40;
    const int cs = (c - gi * 40) * 3 + gi;
    float4 o;
    o.x = fmaf(a0, s, sh); o.y = fmaf(a1, s, sh);
    o.z = fmaf(a2, s, sh); o.w = fmaf(a3, s, sh);
    *reinterpret_cast<float4*>(tmp2 + (size_t)(b * MID + cs) * HWP + hw) = o;
}

// ---------- K3: 1x1 grouped conv (120->480) + BN + ReLU + shortcut, MFMA ----------
// grid (1568, 3), block 256. px-tile 32 (N = 2 x 16), M = 160, K = 40 (pad 64).
__global__ __launch_bounds__(256) void k3_mfma(
    const float* __restrict__ tmp2, const float* __restrict__ w3,
    const float* __restrict__ g3,   const float* __restrict__ b3,
    const float* __restrict__ m3,   const float* __restrict__ v3,
    const float* __restrict__ x,    float* __restrict__ out)
{
    extern __shared__ unsigned short sm[];
    unsigned short* th = sm;                    // tmp2 hi [32][K3RS]
    unsigned short* tl = th + 32 * K3RS;
    unsigned short* wh = tl + 32 * K3RS;        // W3 hi [160][K3RS]
    unsigned short* wl = wh + 160 * K3RS;

    const int tid  = threadIdx.x;
    const int lane = tid & 63;
    const int wv   = tid >> 6;                  // 0..3
    const int g    = blockIdx.y;
    const int p0   = blockIdx.x * 32;
    const int b0   = p0 / HWP;
    const int r0   = p0 - b0 * HWP;

    // ---- stage tmp2 tile (32 px x 40 ic) split bf16 K-major + zero pad ----
    {
        const int px = tid & 31;
        const int iq = tid >> 5;                // 0..7
        int hw = r0 + px, bb = b0;
        if (hw >= HWP) { hw -= HWP; ++bb; }
        const float* __restrict__ tb = tmp2 + (size_t)(bb * MID + g * 40) * HWP + hw;
#pragma unroll
        for (int ii = 0; ii < 5; ++ii) {
            const int ic = iq * 5 + ii;
            unsigned short h, l;
            split2(tb[(size_t)ic * HWP], h, l);
            th[px * K3RS + ic] = h;
            tl[px * K3RS + ic] = l;
        }
#pragma unroll
        for (int ii = 0; ii < 3; ++ii) {
            const int kz = 40 + iq * 3 + ii;
            th[px * K3RS + kz] = 0;
            tl[px * K3RS + kz] = 0;
        }
    }
    // ---- stage W3 tile (160 oc x 40 ic -> 64 padded) split bf16 K-major ----
    {
        const float* __restrict__ wb = w3 + (size_t)(g * 160) * 40;
#pragma unroll
        for (int it = 0; it < 10; ++it) {
            const int task = tid + it * 256;    // < 2560
            const int oc  = task >> 4;
            const int ic0 = (task & 15) * 4;
            float4 wv4 = make_float4(0.f, 0.f, 0.f, 0.f);
            if (ic0 < 40)
                wv4 = *reinterpret_cast<const float4*>(wb + oc * 40 + ic0);
            unsigned short h0, l0, h1, l1, h2, l2, h3, l3;
            split2(wv4.x, h0, l0); split2(wv4.y, h1, l1);
            split2(wv4.z, h2, l2); split2(wv4.w, h3, l3);
            uint2 ph, pl;
            ph.x = (unsigned)h0 | ((unsigned)h1 << 16);
            ph.y = (unsigned)h2 | ((unsigned)h3 << 16);
            pl.x = (unsigned)l0 | ((unsigned)l1 << 16);
            pl.y = (unsigned)l2 | ((unsigned)l3 << 16);
            *reinterpret_cast<uint2*>(&wh[oc * K3RS + ic0]) = ph;
            *reinterpret_cast<uint2*>(&wl[oc * K3RS + ic0]) = pl;
        }
    }
    __syncthreads();

    // ---- MFMA: wave = (mhalf, ntile); 5 M-tiles x 1 N-tile x 2 K-steps ----
    const int ntile = wv & 1;
    const int mh    = wv >> 1;
    f32x4 acc[5];
#pragma unroll
    for (int mt = 0; mt < 5; ++mt) acc[mt] = f32x4{0.f, 0.f, 0.f, 0.f};

    const int n16  = lane & 15;
    const int koff = (lane >> 4) * 8;
    const int brow = ntile * 16 + n16;
#pragma unroll
    for (int ks = 0; ks < 2; ++ks) {
        const int k0 = ks * 32 + koff;
        const bf16x8 Bh = *reinterpret_cast<bf16x8*>(&th[brow * K3RS + k0]);
        const bf16x8 Bl = *reinterpret_cast<bf16x8*>(&tl[brow * K3RS + k0]);
#pragma unroll
        for (int mt = 0; mt < 5; ++mt) {
            const int arow = (mh * 5 + mt) * 16 + n16;
            const bf16x8 Ah = *reinterpret_cast<bf16x8*>(&wh[arow * K3RS + k0]);
            const bf16x8 Al = *reinterpret_cast<bf16x8*>(&wl[arow * K3RS + k0]);
            acc[mt] = __builtin_amdgcn_mfma_f32_16x16x32_bf16(Ah, Bh, acc[mt], 0, 0, 0);
            acc[mt] = __builtin_amdgcn_mfma_f32_16x16x32_bf16(Ah, Bl, acc[mt], 0, 0, 0);
            acc[mt] = __builtin_amdgcn_mfma_f32_16x16x32_bf16(Al, Bh, acc[mt], 0, 0, 0);
        }
    }

    // ---- epilogue: BN + ReLU + fp32 shortcut ----
    {
        const int pj = ntile * 16 + n16;
        int hw = r0 + pj, bb = b0;
        if (hw >= HWP) { hw -= HWP; ++bb; }
        const int rb = (lane >> 4) * 4;
#pragma unroll
        for (int mt = 0; mt < 5; ++mt) {
#pragma unroll
            for (int r = 0; r < 4; ++r) {
                const int ocl = (mh * 5 + mt) * 16 + rb + r;
                const int oc  = g * 160 + ocl;
                const float s  = g3[oc] * rsqrtf(v3[oc] + EPSV);
                const float sh = fmaf(-m3[oc], s, b3[oc]);
                float val = fmaf(acc[mt][r], s, sh);
                val = val > 0.f ? val : 0.f;
                const size_t idx = (size_t)(bb * CIN + oc) * HWP + hw;
                out[idx] = val + x[idx];
            }
        }
    }
}

extern "C" void kernel_launch(void* const* d_in, const int* in_sizes, int n_in,
                              void* d_out, int out_size, void* d_ws, size_t ws_size,
                              hipStream_t stream) {
    const float* x  = (const float*)d_in[0];
    const float* w1 = (const float*)d_in[1];
    const float* g1 = (const float*)d_in[2];
    const float* b1 = (const float*)d_in[3];
    const float* m1 = (const float*)d_in[4];
    const float* v1 = (const float*)d_in[5];
    const float* w2 = (const float*)d_in[6];
    const float* g2 = (const float*)d_in[7];
    const float* b2 = (const float*)d_in[8];
    const float* m2 = (const float*)d_in[9];
    const float* v2 = (const float*)d_in[10];
    const float* w3 = (const float*)d_in[11];
    const float* g3 = (const float*)d_in[12];
    const float* b3 = (const float*)d_in[13];
    const float* m3 = (const float*)d_in[14];
    const float* v3 = (const float*)d_in[15];
    float* out = (float*)d_out;

    float* tmp1 = (float*)d_ws;                       // 24.1 MB
    float* tmp2 = tmp1 + (size_t)64 * MID * HWP;      // 24.1 MB

    hipFuncSetAttribute((const void*)k1_mfma,
                        hipFuncAttributeMaxDynamicSharedMemorySize, K1_SMEM);
    hipFuncSetAttribute((const void*)k3_mfma,
                        hipFuncAttributeMaxDynamicSharedMemorySize, K3_SMEM);

    k1_mfma<<<dim3(784, 3),  256, K1_SMEM, stream>>>(x, w1, g1, b1, m1, v1, tmp1);
    k2_dw  <<<dim3(49, 120), 256, 0,       stream>>>(tmp1, w2, g2, b2, m2, v2, tmp2);
    k3_mfma<<<dim3(1568, 3), 256, K3_SMEM, stream>>>(tmp2, w3, g3, b3, m3, v3, x, out);
}

// Round 7
// 129.734 us; speedup vs baseline: 1.0732x; 1.0732x over previous
//
#include <hip/hip_runtime.h>

// ShuffleNet unit, NCHW. B=64, Cin=Cout=480, mid=120, H=W=28, G=3.
// prep: BN fold + fragment-direct split-bf16 weight packing (+ zero pads).
// K1: conv1 MFMA (split-x in LDS fragment layout, A from packed global).
// K2: dw3x3 + BN + shuffle, output = bf16 in K3's B-fragment layout.
// K3: conv3 MFMA, B direct from global fragments, no staging at all.

namespace {
constexpr int CIN = 480;
constexpr int MID = 120;
constexpr int HWP = 784;
constexpr float EPSV = 1e-5f;

// ws layout (floats): tmp1 [0, 6021120) | G (shorts) | par(1440) | wpk(shorts)
constexpr size_t TMP1_N  = (size_t)64 * MID * HWP;            // 6021120 floats
constexpr size_t G_SHORTS = (size_t)784 * 3 * 4096;           // 9633792 shorts
constexpr size_t G_FLOATS = G_SHORTS / 2;                     // 4816896
constexpr size_t PAR_OFF  = TMP1_N + G_FLOATS;                // float offset
// wpk shorts: wA1h[23040] wA1l[23040] wA3h[30720] wA3l[30720]
constexpr int WA1_N = 3 * 3 * 5 * 64 * 8;                     // 23040
constexpr int WA3_N = 3 * 10 * 2 * 64 * 8;                    // 30720
}

typedef short bf16x8 __attribute__((ext_vector_type(8)));
typedef float f32x4  __attribute__((ext_vector_type(4)));

__device__ inline unsigned short f2bf(float v) {
    unsigned u = __float_as_uint(v);
    return (unsigned short)((u + 0x7fffu + ((u >> 16) & 1u)) >> 16);
}
__device__ inline float bf2f(unsigned short s) {
    return __uint_as_float(((unsigned)s) << 16);
}
__device__ inline void split2(float v, unsigned short& h, unsigned short& l) {
    h = f2bf(v);
    l = f2bf(v - bf2f(h));
}

// ---------------- prep: BN fold + weight frag-packing + G zero-pads ----------------
__global__ __launch_bounds__(256) void prep_k(
    const float* __restrict__ w1, const float* __restrict__ w3,
    const float* __restrict__ g1, const float* __restrict__ b1,
    const float* __restrict__ m1, const float* __restrict__ v1,
    const float* __restrict__ g2, const float* __restrict__ b2,
    const float* __restrict__ m2, const float* __restrict__ v2,
    const float* __restrict__ g3, const float* __restrict__ b3,
    const float* __restrict__ m3, const float* __restrict__ v3,
    float* __restrict__ par, unsigned short* __restrict__ wpk,
    unsigned short* __restrict__ G)
{
    const int t = blockIdx.x * 256 + threadIdx.x;
    if (t < 720) {
        if (t < 120) {
            const float s = g1[t] * rsqrtf(v1[t] + EPSV);
            par[t] = s; par[120 + t] = fmaf(-m1[t], s, b1[t]);
        } else if (t < 240) {
            const int c = t - 120;
            const float s = g2[c] * rsqrtf(v2[c] + EPSV);
            par[240 + c] = s; par[360 + c] = fmaf(-m2[c], s, b2[c]);
        } else {
            const int c = t - 240;
            const float s = g3[c] * rsqrtf(v3[c] + EPSV);
            par[480 + c] = s; par[960 + c] = fmaf(-m3[c], s, b3[c]);
        }
    } else if (t < 3600) {
        // w1 frags: [g][mt<3][ks<5][lane] -> 8 hi + 8 lo bf16
        const int t1   = t - 720;
        const int lane = t1 & 63;
        const int rest = t1 >> 6;           // g*15 + mt*5 + ks
        const int ks   = rest % 5;
        const int mtg  = rest / 5;          // g*3 + mt
        const int mt   = mtg % 3;
        const int g    = mtg / 3;
        const int row  = mt * 16 + (lane & 15);
        const int k0   = ks * 32 + (lane >> 4) * 8;
        unsigned short h[8], l[8];
#pragma unroll
        for (int j = 0; j < 8; ++j) {
            float v = (row < 40) ? w1[(size_t)(g * 40 + row) * 160 + k0 + j] : 0.f;
            split2(v, h[j], l[j]);
        }
        *reinterpret_cast<uint4*>(wpk + (size_t)t1 * 8)           = *reinterpret_cast<uint4*>(h);
        *reinterpret_cast<uint4*>(wpk + WA1_N + (size_t)t1 * 8)   = *reinterpret_cast<uint4*>(l);
    } else if (t < 7440) {
        // w3 frags: [g][mt<10][ks<2][lane]
        const int t3   = t - 3600;
        const int lane = t3 & 63;
        const int rest = t3 >> 6;           // g*20 + mt*2 + ks
        const int ks   = rest % 2;
        const int mtg  = rest / 2;          // g*10 + mt
        const int mt   = mtg % 10;
        const int g    = mtg / 10;
        const int row  = mt * 16 + (lane & 15);
        const int k0   = ks * 32 + (lane >> 4) * 8;
        unsigned short h[8], l[8];
#pragma unroll
        for (int j = 0; j < 8; ++j) {
            const int k = k0 + j;
            float v = (k < 40) ? w3[(size_t)(g * 160 + row) * 40 + k] : 0.f;
            split2(v, h[j], l[j]);
        }
        *reinterpret_cast<uint4*>(wpk + 2 * WA1_N + (size_t)t3 * 8)         = *reinterpret_cast<uint4*>(h);
        *reinterpret_cast<uint4*>(wpk + 2 * WA1_N + WA3_N + (size_t)t3 * 8) = *reinterpret_cast<uint4*>(l);
    } else {
        // zero-fill G pad slabs: per (bx,g): shorts [2560, 4096)
        const int z = t - 7440;
        if (z < 451584) {
            const int tg  = z / 192;        // bx*3 + g
            const int off = z - tg * 192;
            *reinterpret_cast<uint4*>(G + (size_t)tg * 4096 + 2560 + off * 8) =
                make_uint4(0u, 0u, 0u, 0u);
        }
    }
}

// ---------------- K1: conv1 (480->120, G=3) + BN + ReLU, MFMA ----------------
// grid (784, 3), block 256 = 4 waves; 64-px tile, M=48(pad), K=160.
__global__ __launch_bounds__(256) void k1_mfma(
    const float* __restrict__ x, const unsigned short* __restrict__ wA1h,
    const float* __restrict__ par, float* __restrict__ tmp1)
{
    __shared__ __align__(16) unsigned short Bh[10240];   // [nt4][ks5][lane64][8]
    __shared__ __align__(16) unsigned short Bl[10240];
    __shared__ float sL[40], shL[40];

    const int tid  = threadIdx.x;
    const int lane = tid & 63;
    const int wv   = tid >> 6;
    const int g    = blockIdx.y;
    const int p0   = blockIdx.x * 64;
    const int b0   = p0 / HWP;
    const int r0   = p0 - b0 * HWP;

    if (tid < 40) { sL[tid] = par[g * 40 + tid]; shL[tid] = par[120 + g * 40 + tid]; }

    // stage split-x into fragment-direct LDS
    {
        const int px = lane;
        int hw = r0 + px, bb = b0;
        if (hw >= HWP) { hw -= HWP; ++bb; }
        const float* __restrict__ xb = x + ((size_t)bb * CIN + g * 160) * HWP + hw;
        const int nt = px >> 4, n16 = px & 15;
#pragma unroll
        for (int m = 0; m < 5; ++m) {
            const int kb8 = wv + 4 * m;       // 0..19
            const int ic0 = kb8 * 8;
            unsigned hp[4], lp[4];
#pragma unroll
            for (int jj = 0; jj < 4; ++jj) {
                const float va = xb[(size_t)(ic0 + 2 * jj) * HWP];
                const float vb = xb[(size_t)(ic0 + 2 * jj + 1) * HWP];
                unsigned short ha, la, hb, lb;
                split2(va, ha, la); split2(vb, hb, lb);
                hp[jj] = (unsigned)ha | ((unsigned)hb << 16);
                lp[jj] = (unsigned)la | ((unsigned)lb << 16);
            }
            const int ks = kb8 >> 2, kbl = kb8 & 3;
            const int slot = (((nt * 5 + ks) * 4 + kbl) * 16 + n16) * 8;
            *reinterpret_cast<uint4*>(&Bh[slot]) = make_uint4(hp[0], hp[1], hp[2], hp[3]);
            *reinterpret_cast<uint4*>(&Bl[slot]) = make_uint4(lp[0], lp[1], lp[2], lp[3]);
        }
    }
    __syncthreads();

    const unsigned short* __restrict__ wA1l = wA1h + WA1_N;
    f32x4 acc[3];
#pragma unroll
    for (int mt = 0; mt < 3; ++mt) acc[mt] = f32x4{0.f, 0.f, 0.f, 0.f};

    const int nt = wv;
#pragma unroll
    for (int ks = 0; ks < 5; ++ks) {
        const bf16x8 Bhv = *reinterpret_cast<const bf16x8*>(&Bh[((nt * 5 + ks) * 64 + lane) * 8]);
        const bf16x8 Blv = *reinterpret_cast<const bf16x8*>(&Bl[((nt * 5 + ks) * 64 + lane) * 8]);
#pragma unroll
        for (int mt = 0; mt < 3; ++mt) {
            const size_t fi = (((size_t)(g * 3 + mt) * 5 + ks) * 64 + lane) * 8;
            const bf16x8 Ah = *reinterpret_cast<const bf16x8*>(wA1h + fi);
            const bf16x8 Al = *reinterpret_cast<const bf16x8*>(wA1l + fi);
            acc[mt] = __builtin_amdgcn_mfma_f32_16x16x32_bf16(Ah, Bhv, acc[mt], 0, 0, 0);
            acc[mt] = __builtin_amdgcn_mfma_f32_16x16x32_bf16(Ah, Blv, acc[mt], 0, 0, 0);
            acc[mt] = __builtin_amdgcn_mfma_f32_16x16x32_bf16(Al, Bhv, acc[mt], 0, 0, 0);
        }
    }

    // epilogue
    {
        const int n16 = lane & 15, rb = (lane >> 4) * 4;
        int hw = r0 + nt * 16 + n16, bb = b0;
        if (hw >= HWP) { hw -= HWP; ++bb; }
#pragma unroll
        for (int mt = 0; mt < 3; ++mt) {
#pragma unroll
            for (int r = 0; r < 4; ++r) {
                const int ocl = mt * 16 + rb + r;
                if (ocl < 40) {
                    float val = fmaf(acc[mt][r], sL[ocl], shL[ocl]);
                    tmp1[((size_t)bb * MID + g * 40 + ocl) * HWP + hw] = val > 0.f ? val : 0.f;
                }
            }
        }
    }
}

// ---------------- K2: dw3x3 + BN + shuffle -> bf16 fragment layout G ----------------
// grid (784, 4), block 256: thread = 1 px x 8 shuffled channels.
__global__ __launch_bounds__(256) void k2_dw(
    const float* __restrict__ tmp1, const float* __restrict__ w2,
    const float* __restrict__ par, unsigned short* __restrict__ G)
{
    const int bx   = blockIdx.x;
    int cb = blockIdx.y * 4 + (threadIdx.x >> 6);
    cb = __builtin_amdgcn_readfirstlane(cb);
    if (cb >= 15) return;
    const int px64 = threadIdx.x & 63;
    const int px   = bx * 64 + px64;
    const int b    = px / HWP;
    const int hw   = px - b * HWP;
    const int h    = hw / 28, w = hw - h * 28;
    const int nt   = px64 >> 4, n16 = px64 & 15;

    unsigned short res[8];
#pragma unroll
    for (int i = 0; i < 8; ++i) {
        const int cs = cb * 8 + i;
        const int c  = (cs % 3) * 40 + cs / 3;       // inverse shuffle
        const float* __restrict__ tp = tmp1 + ((size_t)b * MID + c) * HWP;
        float a = 0.f;
#pragma unroll
        for (int dh = -1; dh <= 1; ++dh) {
            const int hh = h + dh;
            if (hh < 0 || hh > 27) continue;
#pragma unroll
            for (int dw_ = -1; dw_ <= 1; ++dw_) {
                const int ww = w + dw_;
                if (ww < 0 || ww > 27) continue;
                a = fmaf(tp[hh * 28 + ww], w2[c * 9 + (dh + 1) * 3 + (dw_ + 1)], a);
            }
        }
        res[i] = f2bf(fmaf(a, par[240 + c], par[360 + c]));
    }
    const int gk  = (cb * 8) / 40;
    const int icg = cb * 8 - gk * 40;                // 8-aligned
    const int kb8 = icg >> 3, ks = kb8 >> 2, kbl = kb8 & 3;
    unsigned short* dst = G + (((((size_t)bx * 3 + gk) * 2 + ks) * 4 + kbl) * 4 + nt) * 128 + n16 * 8;
    *reinterpret_cast<uint4*>(dst) = *reinterpret_cast<uint4*>(res);
}

// ---------------- K3: conv3 (120->480) + BN + ReLU + shortcut, MFMA ----------------
// grid (784, 6): g = by>>1, mh = by&1 (M=80). B direct from G; no staging.
__global__ __launch_bounds__(256) void k3_mfma(
    const unsigned short* __restrict__ G, const unsigned short* __restrict__ wA3h,
    const float* __restrict__ par,
    const float* __restrict__ x, float* __restrict__ out)
{
    __shared__ float sL[80], shL[80];
    const int tid  = threadIdx.x;
    const int lane = tid & 63;
    const int wv   = tid >> 6;
    const int bx   = blockIdx.x;
    const int g    = blockIdx.y >> 1;
    const int mh   = blockIdx.y & 1;
    if (tid < 80) {
        sL[tid]  = par[480 + g * 160 + mh * 80 + tid];
        shL[tid] = par[960 + g * 160 + mh * 80 + tid];
    }
    __syncthreads();

    const unsigned short* __restrict__ wA3l = wA3h + WA3_N;
    const int nt = wv;
    f32x4 acc[5];
#pragma unroll
    for (int mt = 0; mt < 5; ++mt) acc[mt] = f32x4{0.f, 0.f, 0.f, 0.f};

    const int kbl = lane >> 4, n16l = lane & 15;
#pragma unroll
    for (int ks = 0; ks < 2; ++ks) {
        const bf16x8 Bv = *reinterpret_cast<const bf16x8*>(
            G + (((((size_t)bx * 3 + g) * 2 + ks) * 4 + kbl) * 4 + nt) * 128 + n16l * 8);
#pragma unroll
        for (int mt = 0; mt < 5; ++mt) {
            const size_t fi = (((size_t)(g * 10 + mh * 5 + mt) * 2 + ks) * 64 + lane) * 8;
            const bf16x8 Ah = *reinterpret_cast<const bf16x8*>(wA3h + fi);
            const bf16x8 Al = *reinterpret_cast<const bf16x8*>(wA3l + fi);
            acc[mt] = __builtin_amdgcn_mfma_f32_16x16x32_bf16(Ah, Bv, acc[mt], 0, 0, 0);
            acc[mt] = __builtin_amdgcn_mfma_f32_16x16x32_bf16(Al, Bv, acc[mt], 0, 0, 0);
        }
    }

    // epilogue: BN + ReLU + fp32 shortcut
    {
        const int n16 = lane & 15, rb = (lane >> 4) * 4;
        const int p0 = bx * 64;
        int hw = p0 % HWP + nt * 16 + n16, bb = p0 / HWP;
        if (hw >= HWP) { hw -= HWP; ++bb; }
#pragma unroll
        for (int mt = 0; mt < 5; ++mt) {
#pragma unroll
            for (int r = 0; r < 4; ++r) {
                const int ocl = mt * 16 + rb + r;
                const int oc  = g * 160 + mh * 80 + ocl;
                const size_t idx = ((size_t)bb * CIN + oc) * HWP + hw;
                float val = fmaf(acc[mt][r], sL[ocl], shL[ocl]);
                val = val > 0.f ? val : 0.f;
                out[idx] = val + x[idx];
            }
        }
    }
}

extern "C" void kernel_launch(void* const* d_in, const int* in_sizes, int n_in,
                              void* d_out, int out_size, void* d_ws, size_t ws_size,
                              hipStream_t stream) {
    const float* x  = (const float*)d_in[0];
    const float* w1 = (const float*)d_in[1];
    const float* g1 = (const float*)d_in[2];
    const float* b1 = (const float*)d_in[3];
    const float* m1 = (const float*)d_in[4];
    const float* v1 = (const float*)d_in[5];
    const float* w2 = (const float*)d_in[6];
    const float* g2 = (const float*)d_in[7];
    const float* b2 = (const float*)d_in[8];
    const float* m2 = (const float*)d_in[9];
    const float* v2 = (const float*)d_in[10];
    const float* w3 = (const float*)d_in[11];
    const float* g3 = (const float*)d_in[12];
    const float* b3 = (const float*)d_in[13];
    const float* m3 = (const float*)d_in[14];
    const float* v3 = (const float*)d_in[15];
    float* out = (float*)d_out;

    float* wsf = (float*)d_ws;
    float* tmp1 = wsf;                                            // 24.08 MB
    unsigned short* G = (unsigned short*)(wsf + TMP1_N);          // 19.27 MB
    float* par = wsf + PAR_OFF;                                   // 1440 floats
    unsigned short* wpk = (unsigned short*)(par + 1440);          // 215 KB

    prep_k<<<1794, 256, 0, stream>>>(w1, w3, g1, b1, m1, v1, g2, b2, m2, v2,
                                     g3, b3, m3, v3, par, wpk, G);
    k1_mfma<<<dim3(784, 3), 256, 0, stream>>>(x, wpk, par, tmp1);
    k2_dw  <<<dim3(784, 4), 256, 0, stream>>>(tmp1, w2, par, G);
    k3_mfma<<<dim3(784, 6), 256, 0, stream>>>(G, wpk + 2 * WA1_N, par, x, out);
}

// Round 8
// 105.827 us; speedup vs baseline: 1.3156x; 1.2259x over previous
//
#include <hip/hip_runtime.h>

// ShuffleNet unit, NCHW. B=64, Cin=Cout=480, mid=120, H=W=28, G=3.
// prep: BN fold + fragment-direct split-bf16 weight packing (+ G zero pads).
// K1: conv1 MFMA; x staged via float4 into fp32 LDS (odd stride), split-on-read.
// K2: dw3x3+BN+shuffle; float4 stencil -> LDS transpose -> bf16x8 G fragments.
// K3: conv3 MFMA, B direct from G; epilogue via LDS transpose -> float4 I/O.

namespace {
constexpr int CIN = 480;
constexpr int MID = 120;
constexpr int HWP = 784;
constexpr float EPSV = 1e-5f;

constexpr size_t TMP1_N   = (size_t)64 * MID * HWP;           // floats
constexpr size_t G_SHORTS = (size_t)784 * 3 * 4096;
constexpr size_t G_FLOATS = G_SHORTS / 2;
constexpr size_t PAR_OFF  = TMP1_N + G_FLOATS;
constexpr int WA1_N = 3 * 3 * 5 * 64 * 8;                     // 23040 shorts
constexpr int WA3_N = 3 * 10 * 2 * 64 * 8;                    // 30720 shorts

constexpr int S1X = 161;   // K1 x-tile LDS stride (odd -> <=2-way banks)
constexpr int S2O = 69;    // K2 out LDS stride (odd)
constexpr int S3O = 67;    // K3 out LDS stride (odd)
}

typedef short bf16x8 __attribute__((ext_vector_type(8)));
typedef float f32x4  __attribute__((ext_vector_type(4)));

__device__ inline unsigned short f2bf(float v) {
    unsigned u = __float_as_uint(v);
    return (unsigned short)((u + 0x7fffu + ((u >> 16) & 1u)) >> 16);
}
__device__ inline float bf2f(unsigned short s) {
    return __uint_as_float(((unsigned)s) << 16);
}
__device__ inline void split2(float v, unsigned short& h, unsigned short& l) {
    h = f2bf(v);
    l = f2bf(v - bf2f(h));
}

// ---------------- prep: BN fold + weight frag-packing + G zero-pads ----------------
__global__ __launch_bounds__(256) void prep_k(
    const float* __restrict__ w1, const float* __restrict__ w3,
    const float* __restrict__ g1, const float* __restrict__ b1,
    const float* __restrict__ m1, const float* __restrict__ v1,
    const float* __restrict__ g2, const float* __restrict__ b2,
    const float* __restrict__ m2, const float* __restrict__ v2,
    const float* __restrict__ g3, const float* __restrict__ b3,
    const float* __restrict__ m3, const float* __restrict__ v3,
    float* __restrict__ par, unsigned short* __restrict__ wpk,
    unsigned short* __restrict__ G)
{
    const int t = blockIdx.x * 256 + threadIdx.x;
    if (t < 720) {
        if (t < 120) {
            const float s = g1[t] * rsqrtf(v1[t] + EPSV);
            par[t] = s; par[120 + t] = fmaf(-m1[t], s, b1[t]);
        } else if (t < 240) {
            const int c = t - 120;
            const float s = g2[c] * rsqrtf(v2[c] + EPSV);
            par[240 + c] = s; par[360 + c] = fmaf(-m2[c], s, b2[c]);
        } else {
            const int c = t - 240;
            const float s = g3[c] * rsqrtf(v3[c] + EPSV);
            par[480 + c] = s; par[960 + c] = fmaf(-m3[c], s, b3[c]);
        }
    } else if (t < 3600) {
        // w1 frags: [g][mt<3][ks<5][lane] -> 8 hi + 8 lo bf16
        const int t1   = t - 720;
        const int lane = t1 & 63;
        const int rest = t1 >> 6;
        const int ks   = rest % 5;
        const int mtg  = rest / 5;
        const int mt   = mtg % 3;
        const int g    = mtg / 3;
        const int row  = mt * 16 + (lane & 15);
        const int k0   = ks * 32 + (lane >> 4) * 8;
        unsigned short h[8], l[8];
#pragma unroll
        for (int j = 0; j < 8; ++j) {
            float v = (row < 40) ? w1[(size_t)(g * 40 + row) * 160 + k0 + j] : 0.f;
            split2(v, h[j], l[j]);
        }
        *reinterpret_cast<uint4*>(wpk + (size_t)t1 * 8)         = *reinterpret_cast<uint4*>(h);
        *reinterpret_cast<uint4*>(wpk + WA1_N + (size_t)t1 * 8) = *reinterpret_cast<uint4*>(l);
    } else if (t < 7440) {
        // w3 frags: [g][mt<10][ks<2][lane]
        const int t3   = t - 3600;
        const int lane = t3 & 63;
        const int rest = t3 >> 6;
        const int ks   = rest % 2;
        const int mtg  = rest / 2;
        const int mt   = mtg % 10;
        const int g    = mtg / 10;
        const int row  = mt * 16 + (lane & 15);
        const int k0   = ks * 32 + (lane >> 4) * 8;
        unsigned short h[8], l[8];
#pragma unroll
        for (int j = 0; j < 8; ++j) {
            const int k = k0 + j;
            float v = (k < 40) ? w3[(size_t)(g * 160 + row) * 40 + k] : 0.f;
            split2(v, h[j], l[j]);
        }
        *reinterpret_cast<uint4*>(wpk + 2 * WA1_N + (size_t)t3 * 8)         = *reinterpret_cast<uint4*>(h);
        *reinterpret_cast<uint4*>(wpk + 2 * WA1_N + WA3_N + (size_t)t3 * 8) = *reinterpret_cast<uint4*>(l);
    } else {
        // zero-fill G pad slabs: per (bx,g): shorts [2560, 4096)
        const int z = t - 7440;
        if (z < 451584) {
            const int tg  = z / 192;
            const int off = z - tg * 192;
            *reinterpret_cast<uint4*>(G + (size_t)tg * 4096 + 2560 + off * 8) =
                make_uint4(0u, 0u, 0u, 0u);
        }
    }
}

// ---------------- K1: conv1 (480->120, G=3) + BN + ReLU, MFMA ----------------
// grid (784, 3), block 256 = 4 waves; 64-px tile, M=48(pad), K=160.
__global__ __launch_bounds__(256) void k1_mfma(
    const float* __restrict__ x, const unsigned short* __restrict__ wA1h,
    const float* __restrict__ par, float* __restrict__ tmp1)
{
    __shared__ float xs[64 * S1X];          // fp32 x tile [px][ch], odd stride
    __shared__ float sL[40], shL[40];

    const int tid  = threadIdx.x;
    const int lane = tid & 63;
    const int wv   = tid >> 6;
    const int g    = blockIdx.y;
    const int p0   = blockIdx.x * 64;

    if (tid < 40) { sL[tid] = par[g * 40 + tid]; shL[tid] = par[120 + g * 40 + tid]; }

    // stage x tile: 160 ch x 16 px4-groups = 2560 float4 tasks, 10/thread
#pragma unroll
    for (int i = 0; i < 10; ++i) {
        const int task = tid + i * 256;
        const int ch   = task >> 4;
        const int px4  = task & 15;
        const int p    = p0 + px4 * 4;
        const int b    = p / HWP;
        const int hw   = p - b * HWP;
        const float4 v = *reinterpret_cast<const float4*>(
            x + ((size_t)b * CIN + g * 160 + ch) * HWP + hw);
        float* d = xs + (px4 * 4) * S1X + ch;
        d[0] = v.x; d[S1X] = v.y; d[2 * S1X] = v.z; d[3 * S1X] = v.w;
    }
    __syncthreads();

    const unsigned short* __restrict__ wA1l = wA1h + WA1_N;
    f32x4 acc[3];
#pragma unroll
    for (int mt = 0; mt < 3; ++mt) acc[mt] = f32x4{0.f, 0.f, 0.f, 0.f};

    const int n16 = lane & 15;
    const int kq  = lane >> 4;
    const int pxl = wv * 16 + n16;
#pragma unroll
    for (int ks = 0; ks < 5; ++ks) {
        const int k0 = ks * 32 + kq * 8;
        const float* bp = xs + pxl * S1X + k0;
        bf16x8 Bh, Bl;
#pragma unroll
        for (int j = 0; j < 8; ++j) {
            unsigned short h, l;
            split2(bp[j], h, l);
            Bh[j] = (short)h; Bl[j] = (short)l;
        }
#pragma unroll
        for (int mt = 0; mt < 3; ++mt) {
            const size_t fi = (((size_t)(g * 3 + mt) * 5 + ks) * 64 + lane) * 8;
            const bf16x8 Ah = *reinterpret_cast<const bf16x8*>(wA1h + fi);
            const bf16x8 Al = *reinterpret_cast<const bf16x8*>(wA1l + fi);
            acc[mt] = __builtin_amdgcn_mfma_f32_16x16x32_bf16(Ah, Bh, acc[mt], 0, 0, 0);
            acc[mt] = __builtin_amdgcn_mfma_f32_16x16x32_bf16(Ah, Bl, acc[mt], 0, 0, 0);
            acc[mt] = __builtin_amdgcn_mfma_f32_16x16x32_bf16(Al, Bh, acc[mt], 0, 0, 0);
        }
    }

    // epilogue: BN + ReLU, scalar stores (channel-strided)
    {
        int hw = (p0 % HWP) + pxl, bb = p0 / HWP;
        if (hw >= HWP) { hw -= HWP; ++bb; }
        const int rb = kq * 4;
#pragma unroll
        for (int mt = 0; mt < 3; ++mt) {
#pragma unroll
            for (int r = 0; r < 4; ++r) {
                const int ocl = mt * 16 + rb + r;
                if (ocl < 40) {
                    float val = fmaf(acc[mt][r], sL[ocl], shL[ocl]);
                    tmp1[((size_t)bb * MID + g * 40 + ocl) * HWP + hw] = val > 0.f ? val : 0.f;
                }
            }
        }
    }
}

// ---------------- K2: dw3x3 + BN + shuffle -> bf16 G fragments ----------------
// grid (784), block 256. Tile = 64 px x all 120 ch.
__global__ __launch_bounds__(256) void k2_dw(
    const float* __restrict__ tmp1, const float* __restrict__ w2,
    const float* __restrict__ par, unsigned short* __restrict__ G)
{
    __shared__ float dout[MID * S2O];       // [shuffled ch][px], odd stride
    __shared__ float w2s[1080];
    __shared__ float s2s[120], sh2s[120];

    const int tid = threadIdx.x;
    const int bx  = blockIdx.x;
    const int p0  = bx * 64;

    for (int i = tid; i < 1080; i += 256) w2s[i] = w2[i];
    if (tid < 120) { s2s[tid] = par[240 + tid]; sh2s[tid] = par[360 + tid]; }
    __syncthreads();

    // phase A: stencil, 120 ch x 16 px4 = 1920 tasks
#pragma unroll
    for (int i = 0; i < 8; ++i) {
        const int task = tid + i * 256;
        if (task < 1920) {
            const int ch  = task >> 4;
            const int px4 = task & 15;
            const int p   = p0 + px4 * 4;
            const int b   = p / HWP;
            const int hw  = p - b * HWP;
            const int h   = hw / 28, w = hw - h * 28;
            const float* __restrict__ in = tmp1 + ((size_t)b * MID + ch) * HWP;
            const float* wk = w2s + ch * 9;

            float a0 = 0.f, a1 = 0.f, a2 = 0.f, a3 = 0.f;
#pragma unroll
            for (int dh = -1; dh <= 1; ++dh) {
                const int hh = h + dh;
                if (hh < 0 || hh > 27) continue;
                const float* r = in + hh * 28 + w;
                const float4 c4 = *reinterpret_cast<const float4*>(r);
                const float cl = (w > 0)  ? r[-1] : 0.f;
                const float cr = (w < 24) ? r[4]  : 0.f;
                const float* wr = wk + (dh + 1) * 3;
                a0 = fmaf(cl,   wr[0], a0); a0 = fmaf(c4.x, wr[1], a0); a0 = fmaf(c4.y, wr[2], a0);
                a1 = fmaf(c4.x, wr[0], a1); a1 = fmaf(c4.y, wr[1], a1); a1 = fmaf(c4.z, wr[2], a1);
                a2 = fmaf(c4.y, wr[0], a2); a2 = fmaf(c4.z, wr[1], a2); a2 = fmaf(c4.w, wr[2], a2);
                a3 = fmaf(c4.z, wr[0], a3); a3 = fmaf(c4.w, wr[1], a3); a3 = fmaf(cr,   wr[2], a3);
            }
            const float s  = s2s[ch];
            const float sh = sh2s[ch];
            const int gi = ch / 40;
            const int cs = (ch - gi * 40) * 3 + gi;        // channel shuffle
            float* d = dout + cs * S2O + px4 * 4;
            d[0] = fmaf(a0, s, sh); d[1] = fmaf(a1, s, sh);
            d[2] = fmaf(a2, s, sh); d[3] = fmaf(a3, s, sh);
        }
    }
    __syncthreads();

    // phase B: pack 8 shuffled ch x 1 px -> 16B G store. 15 cb x 64 px = 960 tasks
#pragma unroll
    for (int i = 0; i < 4; ++i) {
        const int task = tid + i * 256;
        if (task < 960) {
            const int cb  = task >> 6;          // wave-uniform
            const int pxl = task & 63;
            const int cs0 = cb * 8;
            unsigned short res[8];
#pragma unroll
            for (int j = 0; j < 8; ++j)
                res[j] = f2bf(dout[(cs0 + j) * S2O + pxl]);
            const int gk  = cs0 / 40;
            const int icg = cs0 - gk * 40;
            const int kb8 = icg >> 3, ks = kb8 >> 2, kbl = kb8 & 3;
            const int nt  = pxl >> 4, n16 = pxl & 15;
            unsigned short* dst = G +
                (((((size_t)bx * 3 + gk) * 2 + ks) * 4 + kbl) * 4 + nt) * 128 + n16 * 8;
            *reinterpret_cast<uint4*>(dst) = *reinterpret_cast<uint4*>(res);
        }
    }
}

// ---------------- K3: conv3 (120->480) + BN + ReLU + shortcut, MFMA ----------------
// grid (784, 6): g = by>>1, mh = by&1 (M=80). B direct from G; LDS-transposed epilogue.
__global__ __launch_bounds__(256) void k3_mfma(
    const unsigned short* __restrict__ G, const unsigned short* __restrict__ wA3h,
    const float* __restrict__ par,
    const float* __restrict__ x, float* __restrict__ out)
{
    __shared__ float osr[80 * S3O];
    __shared__ float sL[80], shL[80];

    const int tid  = threadIdx.x;
    const int lane = tid & 63;
    const int wv   = tid >> 6;
    const int bx   = blockIdx.x;
    const int g    = blockIdx.y >> 1;
    const int mh   = blockIdx.y & 1;
    if (tid < 80) {
        sL[tid]  = par[480 + g * 160 + mh * 80 + tid];
        shL[tid] = par[960 + g * 160 + mh * 80 + tid];
    }
    __syncthreads();

    const unsigned short* __restrict__ wA3l = wA3h + WA3_N;
    const int nt = wv;
    f32x4 acc[5];
#pragma unroll
    for (int mt = 0; mt < 5; ++mt) acc[mt] = f32x4{0.f, 0.f, 0.f, 0.f};

    const int kbl = lane >> 4, n16l = lane & 15;
#pragma unroll
    for (int ks = 0; ks < 2; ++ks) {
        const bf16x8 Bv = *reinterpret_cast<const bf16x8*>(
            G + (((((size_t)bx * 3 + g) * 2 + ks) * 4 + kbl) * 4 + nt) * 128 + n16l * 8);
#pragma unroll
        for (int mt = 0; mt < 5; ++mt) {
            const size_t fi = (((size_t)(g * 10 + mh * 5 + mt) * 2 + ks) * 64 + lane) * 8;
            const bf16x8 Ah = *reinterpret_cast<const bf16x8*>(wA3h + fi);
            const bf16x8 Al = *reinterpret_cast<const bf16x8*>(wA3l + fi);
            acc[mt] = __builtin_amdgcn_mfma_f32_16x16x32_bf16(Ah, Bv, acc[mt], 0, 0, 0);
            acc[mt] = __builtin_amdgcn_mfma_f32_16x16x32_bf16(Al, Bv, acc[mt], 0, 0, 0);
        }
    }

    // epilogue phase A: BN + ReLU -> LDS transpose
    {
        const int n16 = lane & 15, kq = lane >> 4;
        const int pxl = nt * 16 + n16;
#pragma unroll
        for (int mt = 0; mt < 5; ++mt) {
#pragma unroll
            for (int r = 0; r < 4; ++r) {
                const int ocl = mt * 16 + kq * 4 + r;
                float val = fmaf(acc[mt][r], sL[ocl], shL[ocl]);
                osr[ocl * S3O + pxl] = val > 0.f ? val : 0.f;
            }
        }
    }
    __syncthreads();

    // epilogue phase B: float4 shortcut-read + out-write. 80 ocl x 16 px4 = 1280 tasks
#pragma unroll
    for (int i = 0; i < 5; ++i) {
        const int task = tid + i * 256;
        const int ocl  = task >> 4;
        const int px4  = task & 15;
        const int p    = bx * 64 + px4 * 4;
        const int b    = p / HWP;
        const int hw   = p - b * HWP;
        const int oc   = g * 160 + mh * 80 + ocl;
        const size_t idx = ((size_t)b * CIN + oc) * HWP + hw;
        const float* s = osr + ocl * S3O + px4 * 4;
        const float4 sc = *reinterpret_cast<const float4*>(x + idx);
        float4 o;
        o.x = s[0] + sc.x; o.y = s[1] + sc.y;
        o.z = s[2] + sc.z; o.w = s[3] + sc.w;
        *reinterpret_cast<float4*>(out + idx) = o;
    }
}

extern "C" void kernel_launch(void* const* d_in, const int* in_sizes, int n_in,
                              void* d_out, int out_size, void* d_ws, size_t ws_size,
                              hipStream_t stream) {
    const float* x  = (const float*)d_in[0];
    const float* w1 = (const float*)d_in[1];
    const float* g1 = (const float*)d_in[2];
    const float* b1 = (const float*)d_in[3];
    const float* m1 = (const float*)d_in[4];
    const float* v1 = (const float*)d_in[5];
    const float* w2 = (const float*)d_in[6];
    const float* g2 = (const float*)d_in[7];
    const float* b2 = (const float*)d_in[8];
    const float* m2 = (const float*)d_in[9];
    const float* v2 = (const float*)d_in[10];
    const float* w3 = (const float*)d_in[11];
    const float* g3 = (const float*)d_in[12];
    const float* b3 = (const float*)d_in[13];
    const float* m3 = (const float*)d_in[14];
    const float* v3 = (const float*)d_in[15];
    float* out = (float*)d_out;

    float* wsf = (float*)d_ws;
    float* tmp1 = wsf;                                            // 24.08 MB
    unsigned short* G = (unsigned short*)(wsf + TMP1_N);          // 19.27 MB
    float* par = wsf + PAR_OFF;                                   // 1440 floats
    unsigned short* wpk = (unsigned short*)(par + 1440);          // 215 KB

    prep_k<<<1794, 256, 0, stream>>>(w1, w3, g1, b1, m1, v1, g2, b2, m2, v2,
                                     g3, b3, m3, v3, par, wpk, G);
    k1_mfma<<<dim3(784, 3), 256, 0, stream>>>(x, wpk, par, tmp1);
    k2_dw  <<<784,          256, 0, stream>>>(tmp1, w2, par, G);
    k3_mfma<<<dim3(784, 6), 256, 0, stream>>>(G, wpk + 2 * WA1_N, par, x, out);
}